// Round 13
// baseline (265.333 us; speedup 1.0000x reference)
//
#include <hip/hip_runtime.h>

#define IN_DIM 256
#define EMB 128
// bucket = dst >> 9 (512 nodes per bucket). Requires N <= 131072 (src packed in 17 bits).
#define BKT_SHIFT 9
#define BKT_NODES 512
#define BINE 4096       // edges per bin_scatter block
#define SCAP 12288      // bucket_sort LDS staging capacity (mean ~8163, huge margin)

typedef __attribute__((ext_vector_type(8))) short short8;
typedef __attribute__((ext_vector_type(4))) float f32x4;

__device__ __forceinline__ unsigned short bf16rtne(float f) {
    unsigned int u = __float_as_uint(f);
    return (unsigned short)((u + 0x7fffu + ((u >> 16) & 1u)) >> 16);
}

__device__ __forceinline__ unsigned int packbf2(float lo, float hi) {
    return ((unsigned int)bf16rtne(hi) << 16) | (unsigned int)bf16rtne(lo);
}

// packed f32x8 -> bf16x8 via native cvt_pk (RNE)
__device__ __forceinline__ short8 pack8(float4 f0, float4 f1) {
    union { uint4 u; short8 s; } U;
    asm("v_cvt_pk_bf16_f32 %0, %1, %2" : "=v"(U.u.x) : "v"(f0.x), "v"(f0.y));
    asm("v_cvt_pk_bf16_f32 %0, %1, %2" : "=v"(U.u.y) : "v"(f0.z), "v"(f0.w));
    asm("v_cvt_pk_bf16_f32 %0, %1, %2" : "=v"(U.u.z) : "v"(f1.x), "v"(f1.y));
    asm("v_cvt_pk_bf16_f32 %0, %1, %2" : "=v"(U.u.w) : "v"(f1.z), "v"(f1.w));
    return U.s;
}

// ---------------- fused prep: wt_cast + x_cast + bucket_hist ----------------

__global__ __launch_bounds__(256) void prep(const float* __restrict__ W,
                                            unsigned short* __restrict__ wtg,
                                            const float* __restrict__ x,
                                            unsigned short* __restrict__ xb, int total8,
                                            const int* __restrict__ dst,
                                            int* __restrict__ ghist, int E) {
    int t = threadIdx.x;
    int gsz = gridDim.x * 256;
    int gid = blockIdx.x * 256 + t;
    // W^T cast: wtg[c][k] = bf16(W[k][c])
    for (int i = gid; i < IN_DIM * EMB; i += gsz) {
        int c = i & 127;
        int k = i >> 7;
        wtg[c * 256 + k] = bf16rtne(W[(size_t)k * 128 + c]);
    }
    // x cast (vectorized)
    for (int i = gid; i < total8; i += gsz) {
        const float4* s = (const float4*)(x + (size_t)i * 8);
        *(short8*)(xb + (size_t)i * 8) = pack8(s[0], s[1]);
    }
    // bucket histogram
    __shared__ int h[256];
    h[t] = 0;
    __syncthreads();
    for (int i = gid; i < E; i += gsz) atomicAdd(&h[dst[i] >> BKT_SHIFT], 1);
    __syncthreads();
    if (h[t]) atomicAdd(&ghist[t], h[t]);
}

// single block: exclusive scan of bucket counts -> bucket_off, gcursor
__global__ __launch_bounds__(256) void bucket_scan(const int* __restrict__ ghist,
                                                   int* __restrict__ bucket_off,
                                                   int* __restrict__ gcursor,
                                                   int* __restrict__ row_ptr,
                                                   int NB, int N, int E) {
    __shared__ int s[256];
    int t = threadIdx.x;
    int v = (t < NB) ? ghist[t] : 0;
    s[t] = v;
    __syncthreads();
    for (int off = 1; off < 256; off <<= 1) {
        int u = (t >= off) ? s[t - off] : 0;
        __syncthreads();
        s[t] += u;
        __syncthreads();
    }
    int excl = s[t] - v;
    if (t < NB) {
        bucket_off[t] = excl;
        gcursor[t] = excl;
    }
    if (t == 0) {
        bucket_off[NB] = E;
        row_ptr[N] = E;
    }
}

// ---------------- CSR build: bin edges by bucket, LDS-staged, streaming out ----------------

__global__ __launch_bounds__(512) void bin_scatter(const int* __restrict__ src,
                                                   const int* __restrict__ dst,
                                                   const float* __restrict__ w,
                                                   int* __restrict__ gcursor,
                                                   int2* __restrict__ binned, int E) {
    __shared__ int h[256];
    __shared__ int lbase[256];
    __shared__ int gbase[256];
    __shared__ int lcur[256];
    __shared__ int2 stage[BINE];         // 32 KB
    __shared__ unsigned char sb[BINE];   // slot -> bucket, 4 KB
    int t = threadIdx.x;
    int e0 = blockIdx.x * BINE;
    int e1 = min(E, e0 + BINE);
    int n = e1 - e0;

    int ed[8], es[8];
    float ewv[8];
#pragma unroll
    for (int j = 0; j < 8; ++j) {
        int i = e0 + t + j * 512;
        if (i < e1) {
            ed[j] = dst[i];
            es[j] = src[i];
            ewv[j] = w[i];
        } else
            ed[j] = -1;
    }
    if (t < 256) h[t] = 0;
    __syncthreads();
#pragma unroll
    for (int j = 0; j < 8; ++j)
        if (ed[j] >= 0) atomicAdd(&h[ed[j] >> BKT_SHIFT], 1);
    __syncthreads();
    int v = 0;
    if (t < 256) {
        v = h[t];
        lbase[t] = v;
    }
    __syncthreads();
    for (int off = 1; off < 256; off <<= 1) {
        int u = 0;
        if (t < 256 && t >= off) u = lbase[t - off];
        __syncthreads();
        if (t < 256) lbase[t] += u;
        __syncthreads();
    }
    if (t < 256) {
        lbase[t] -= v;  // exclusive
        lcur[t] = lbase[t];
        gbase[t] = v ? atomicAdd(&gcursor[t], v) : 0;
    }
    __syncthreads();
#pragma unroll
    for (int j = 0; j < 8; ++j) {
        if (ed[j] >= 0) {
            int b = ed[j] >> BKT_SHIFT;
            int p = atomicAdd(&lcur[b], 1);
            int2 r;
            r.x = es[j] | ((ed[j] & (BKT_NODES - 1)) << 17);
            r.y = __float_as_int(ewv[j]);
            stage[p] = r;
            sb[p] = (unsigned char)b;
        }
    }
    __syncthreads();
    for (int i = t; i < n; i += 512) {
        int b = sb[i];
        binned[gbase[b] + (i - lbase[b])] = stage[i];
    }
}

// ---------------- CSR build: per-bucket counting sort, LDS-staged, streaming out ----------------

__global__ __launch_bounds__(1024) void bucket_sort(const int2* __restrict__ binned,
                                                    const int* __restrict__ bucket_off,
                                                    int2* __restrict__ sorted,
                                                    int* __restrict__ row_ptr, int N) {
    __shared__ int cnt[BKT_NODES];
    __shared__ int cur[BKT_NODES];
    __shared__ int scn[BKT_NODES];
    __shared__ int2 stage[SCAP];  // 96 KB
    int t = threadIdx.x;
    int b = blockIdx.x;
    int node0 = b << BKT_SHIFT;
    int nn = min(BKT_NODES, N - node0);
    int beg = bucket_off[b];
    int endb = bucket_off[b + 1];
    int n = endb - beg;
    if (t < BKT_NODES) cnt[t] = 0;
    __syncthreads();
    for (int i = beg + t; i < endb; i += 1024) {
        int ld = ((unsigned int)binned[i].x) >> 17;
        atomicAdd(&cnt[ld], 1);
    }
    __syncthreads();
    int v = 0;
    if (t < BKT_NODES) {
        v = cnt[t];
        scn[t] = v;
    }
    __syncthreads();
    for (int off = 1; off < BKT_NODES; off <<= 1) {
        int u = 0;
        if (t < BKT_NODES && t >= off) u = scn[t - off];
        __syncthreads();
        if (t < BKT_NODES) scn[t] += u;
        __syncthreads();
    }
    if (t < BKT_NODES) {
        int excl = scn[t] - v;
        cur[t] = excl;
        if (t < nn) row_ptr[node0 + t] = beg + excl;
    }
    __syncthreads();
    if (n <= SCAP) {
        for (int i = beg + t; i < endb; i += 1024) {
            int2 r = binned[i];
            int ld = ((unsigned int)r.x) >> 17;
            int p = atomicAdd(&cur[ld], 1);
            r.x &= 0x1FFFF;
            stage[p] = r;
        }
        __syncthreads();
        for (int i = t; i < n; i += 1024) sorted[beg + i] = stage[i];  // sequential
    } else {
        for (int i = beg + t; i < endb; i += 1024) {
            int2 r = binned[i];
            int ld = ((unsigned int)r.x) >> 17;
            int p = atomicAdd(&cur[ld], 1);
            r.x &= 0x1FFFF;
            sorted[beg + p] = r;
        }
    }
}

// ---------------- MFMA GEMM: h = relu(xb@W + b), output bf16 ----------------
// m97 pattern: 128x128 tile, BK=64, 4 waves, global_load_lds with pre-swizzled
// source; frag ds_read_b128 uses the same XOR -> conflict-free.

__global__ __launch_bounds__(256) void gemm_mfma(const unsigned short* __restrict__ xb,
                                                 const unsigned short* __restrict__ wtg,
                                                 const float* __restrict__ bias,
                                                 unsigned short* __restrict__ hbf, int N) {
    __shared__ unsigned short As[128][64];  // 16 KB
    __shared__ unsigned short Bs[128][64];  // 16 KB
    int tid = threadIdx.x;
    int wv = tid >> 6;
    int lane = tid & 63;
    int lr = lane & 15;
    int lg = lane >> 4;
    int wr = wv * 32;
    int row0 = blockIdx.x * 128;

    f32x4 acc[2][8];
#pragma unroll
    for (int m = 0; m < 2; ++m)
#pragma unroll
        for (int n = 0; n < 8; ++n) acc[m][n] = (f32x4){0.f, 0.f, 0.f, 0.f};

    int p0 = wv * 4 * 64 + lane;

    for (int kb = 0; kb < IN_DIM; kb += 64) {
#pragma unroll
        for (int i = 0; i < 4; ++i) {
            int p = p0 + i * 64;
            int r = p >> 3;
            int c = p & 7;
            int cs = (c ^ (r & 7)) * 8;
            int gr = row0 + r;
            if (gr >= N) gr = N - 1;
            const unsigned short* ga = xb + (size_t)gr * IN_DIM + kb + cs;
            __builtin_amdgcn_global_load_lds(
                (const __attribute__((address_space(1))) void*)ga,
                (__attribute__((address_space(3))) void*)((char*)&As[0][0] + (size_t)(wv * 4 + i) * 1024),
                16, 0, 0);
            const unsigned short* gb = wtg + (size_t)r * IN_DIM + kb + cs;
            __builtin_amdgcn_global_load_lds(
                (const __attribute__((address_space(1))) void*)gb,
                (__attribute__((address_space(3))) void*)((char*)&Bs[0][0] + (size_t)(wv * 4 + i) * 1024),
                16, 0, 0);
        }
        __syncthreads();

        short8 a[2][2];
#pragma unroll
        for (int m = 0; m < 2; ++m)
#pragma unroll
            for (int kk = 0; kk < 2; ++kk) {
                int r = wr + m * 16 + lr;
                int ch = kk * 4 + lg;
                a[m][kk] = *(const short8*)&As[r][((ch ^ (r & 7)) * 8)];
            }
#pragma unroll
        for (int n = 0; n < 8; ++n) {
            int cc = n * 16 + lr;
            int sw = cc & 7;
            short8 b0 = *(const short8*)&Bs[cc][(((0 * 4 + lg) ^ sw) * 8)];
            short8 b1 = *(const short8*)&Bs[cc][(((1 * 4 + lg) ^ sw) * 8)];
            acc[0][n] = __builtin_amdgcn_mfma_f32_16x16x32_bf16(a[0][0], b0, acc[0][n], 0, 0, 0);
            acc[0][n] = __builtin_amdgcn_mfma_f32_16x16x32_bf16(a[0][1], b1, acc[0][n], 0, 0, 0);
            acc[1][n] = __builtin_amdgcn_mfma_f32_16x16x32_bf16(a[1][0], b0, acc[1][n], 0, 0, 0);
            acc[1][n] = __builtin_amdgcn_mfma_f32_16x16x32_bf16(a[1][1], b1, acc[1][n], 0, 0, 0);
        }
        __syncthreads();
    }

#pragma unroll
    for (int n = 0; n < 8; ++n) {
        int c = n * 16 + lr;
        float bv = bias[c];
#pragma unroll
        for (int m = 0; m < 2; ++m) {
#pragma unroll
            for (int j = 0; j < 4; ++j) {
                int r = row0 + wr + m * 16 + lg * 4 + j;
                if (r < N) {
                    float v = fmaxf(acc[m][n][j] + bv, 0.f);
                    hbf[(size_t)r * EMB + c] = bf16rtne(v);
                }
            }
        }
    }
}

// ---------------- propagation: wave per node, scalar edge loads, 16-deep gathers ----
// beg/end are wave-uniform -> rec[idx] with uniform idx compiles to s_load on
// the scalar pipe (no per-lane readlane VALU). 16 gathers in flight per batch.

template <int OUTBF>
__global__ __launch_bounds__(256) void prop_g(const unsigned int* __restrict__ hin,
                                              void* __restrict__ hout,
                                              const int* __restrict__ rp,
                                              const int2* __restrict__ rec, int N) {
    int wvid = threadIdx.x >> 6;
    int lane = threadIdx.x & 63;
    int node = blockIdx.x * 4 + wvid;
    if (node >= N) return;
    int beg = __builtin_amdgcn_readfirstlane(rp[node]);
    int end = __builtin_amdgcn_readfirstlane(rp[node + 1]);
    float ax = 0.f, ay = 0.f;
    for (int c0 = beg; c0 < end; c0 += 16) {
        int cnt = end - c0;
        if (cnt > 16) cnt = 16;
        unsigned g[16];
        float w[16];
#pragma unroll
        for (int k = 0; k < 16; ++k) {
            int idx = c0 + (k < cnt ? k : cnt - 1);  // uniform -> s_cselect + s_load
            int2 r = rec[idx];
            w[k] = (k < cnt) ? __int_as_float(r.y) : 0.f;
            g[k] = hin[(size_t)r.x * 64 + lane];
        }
#pragma unroll
        for (int k = 0; k < 16; ++k) {
            ax = fmaf(w[k], __uint_as_float(g[k] << 16), ax);
            ay = fmaf(w[k], __uint_as_float(g[k] & 0xffff0000u), ay);
        }
    }
    if (OUTBF) {
        ((unsigned int*)hout)[(size_t)node * 64 + lane] = packbf2(ax, ay);
    } else {
        float2 o;
        o.x = ax;
        o.y = ay;
        ((float2*)hout)[(size_t)node * 64 + lane] = o;
    }
}

// ---------------- launch ----------------

extern "C" void kernel_launch(void* const* d_in, const int* in_sizes, int n_in,
                              void* d_out, int out_size, void* d_ws, size_t ws_size,
                              hipStream_t stream) {
    const float* x = (const float*)d_in[0];
    const float* W = (const float*)d_in[1];
    const float* b = (const float*)d_in[2];
    const int* esrc = (const int*)d_in[3];
    const int* edst = (const int*)d_in[4];
    const float* ew = (const float*)d_in[5];
    int N = in_sizes[0] / IN_DIM;
    int E = in_sizes[3];
    int NB = (N + BKT_NODES - 1) >> BKT_SHIFT;  // 196

    char* p = (char*)d_ws;
    auto alloc = [&](size_t bytes) -> void* {
        void* r = (void*)p;
        p += (bytes + 255) & ~(size_t)255;
        return r;
    };
    unsigned short* hbf = (unsigned short*)alloc((size_t)N * EMB * 2);
    unsigned short* h1bf = (unsigned short*)alloc((size_t)N * EMB * 2);
    unsigned short* wtg = (unsigned short*)alloc((size_t)IN_DIM * EMB * 2);
    unsigned short* xbf = (unsigned short*)alloc((size_t)N * IN_DIM * 2);
    int* ghist = (int*)alloc(256 * 4);
    int* gcursor = (int*)alloc(256 * 4);
    int* bucket_off = (int*)alloc((size_t)(NB + 1) * 4);
    int* row_ptr = (int*)alloc((size_t)(N + 1) * 4);
    int2* binned = (int2*)alloc((size_t)E * 8);
    int2* sorted = (int2*)alloc((size_t)E * 8);

    hipMemsetAsync(ghist, 0, 256 * 4, stream);
    prep<<<2048, 256, 0, stream>>>(W, wtg, x, xbf, N * IN_DIM / 8, edst, ghist, E);
    bucket_scan<<<1, 256, 0, stream>>>(ghist, bucket_off, gcursor, row_ptr, NB, N, E);
    bin_scatter<<<(E + BINE - 1) / BINE, 512, 0, stream>>>(esrc, edst, ew, gcursor, binned, E);
    bucket_sort<<<NB, 1024, 0, stream>>>(binned, bucket_off, sorted, row_ptr, N);

    gemm_mfma<<<(N + 127) / 128, 256, 0, stream>>>(xbf, wtg, b, hbf, N);
    prop_g<1><<<(N + 3) / 4, 256, 0, stream>>>((const unsigned int*)hbf, h1bf, row_ptr, sorted, N);
    prop_g<0><<<(N + 3) / 4, 256, 0, stream>>>((const unsigned int*)h1bf, d_out, row_ptr, sorted, N);
}

// Round 14
// 244.079 us; speedup vs baseline: 1.0871x; 1.0871x over previous
//
#include <hip/hip_runtime.h>

#define IN_DIM 256
#define EMB 128
// bucket = dst >> 9 (512 nodes per bucket). Requires N <= 131072 (src packed in 17 bits).
#define BKT_SHIFT 9
#define BKT_NODES 512
#define BINE 4096       // edges per bin_scatter block
#define SCAP 12288      // bucket_sort LDS staging capacity (mean ~8163, huge margin)

typedef __attribute__((ext_vector_type(8))) short short8;
typedef __attribute__((ext_vector_type(4))) float f32x4;

__device__ __forceinline__ unsigned short bf16rtne(float f) {
    unsigned int u = __float_as_uint(f);
    return (unsigned short)((u + 0x7fffu + ((u >> 16) & 1u)) >> 16);
}

__device__ __forceinline__ unsigned int packbf2(float lo, float hi) {
    return ((unsigned int)bf16rtne(hi) << 16) | (unsigned int)bf16rtne(lo);
}

// packed f32x8 -> bf16x8 via native cvt_pk (RNE)
__device__ __forceinline__ short8 pack8(float4 f0, float4 f1) {
    union { uint4 u; short8 s; } U;
    asm("v_cvt_pk_bf16_f32 %0, %1, %2" : "=v"(U.u.x) : "v"(f0.x), "v"(f0.y));
    asm("v_cvt_pk_bf16_f32 %0, %1, %2" : "=v"(U.u.y) : "v"(f0.z), "v"(f0.w));
    asm("v_cvt_pk_bf16_f32 %0, %1, %2" : "=v"(U.u.z) : "v"(f1.x), "v"(f1.y));
    asm("v_cvt_pk_bf16_f32 %0, %1, %2" : "=v"(U.u.w) : "v"(f1.z), "v"(f1.w));
    return U.s;
}

// ---------------- fused prep: wt_cast + x_cast + bucket_hist ----------------

__global__ __launch_bounds__(256) void prep(const float* __restrict__ W,
                                            unsigned short* __restrict__ wtg,
                                            const float* __restrict__ x,
                                            unsigned short* __restrict__ xb, int total8,
                                            const int* __restrict__ dst,
                                            int* __restrict__ ghist, int E) {
    int t = threadIdx.x;
    int gsz = gridDim.x * 256;
    int gid = blockIdx.x * 256 + t;
    for (int i = gid; i < IN_DIM * EMB; i += gsz) {
        int c = i & 127;
        int k = i >> 7;
        wtg[c * 256 + k] = bf16rtne(W[(size_t)k * 128 + c]);
    }
    for (int i = gid; i < total8; i += gsz) {
        const float4* s = (const float4*)(x + (size_t)i * 8);
        *(short8*)(xb + (size_t)i * 8) = pack8(s[0], s[1]);
    }
    __shared__ int h[256];
    h[t] = 0;
    __syncthreads();
    for (int i = gid; i < E; i += gsz) atomicAdd(&h[dst[i] >> BKT_SHIFT], 1);
    __syncthreads();
    if (h[t]) atomicAdd(&ghist[t], h[t]);
}

// single block: exclusive scan of bucket counts -> bucket_off, gcursor
__global__ __launch_bounds__(256) void bucket_scan(const int* __restrict__ ghist,
                                                   int* __restrict__ bucket_off,
                                                   int* __restrict__ gcursor,
                                                   int* __restrict__ row_ptr,
                                                   int NB, int N, int E) {
    __shared__ int s[256];
    int t = threadIdx.x;
    int v = (t < NB) ? ghist[t] : 0;
    s[t] = v;
    __syncthreads();
    for (int off = 1; off < 256; off <<= 1) {
        int u = (t >= off) ? s[t - off] : 0;
        __syncthreads();
        s[t] += u;
        __syncthreads();
    }
    int excl = s[t] - v;
    if (t < NB) {
        bucket_off[t] = excl;
        gcursor[t] = excl;
    }
    if (t == 0) {
        bucket_off[NB] = E;
        row_ptr[N] = E;
    }
}

// ---------------- CSR build: bin edges by bucket, LDS-staged, streaming out ----------------

__global__ __launch_bounds__(512) void bin_scatter(const int* __restrict__ src,
                                                   const int* __restrict__ dst,
                                                   const float* __restrict__ w,
                                                   int* __restrict__ gcursor,
                                                   int2* __restrict__ binned, int E) {
    __shared__ int h[256];
    __shared__ int lbase[256];
    __shared__ int gbase[256];
    __shared__ int lcur[256];
    __shared__ int2 stage[BINE];         // 32 KB
    __shared__ unsigned char sb[BINE];   // slot -> bucket, 4 KB
    int t = threadIdx.x;
    int e0 = blockIdx.x * BINE;
    int e1 = min(E, e0 + BINE);
    int n = e1 - e0;

    int ed[8], es[8];
    float ewv[8];
#pragma unroll
    for (int j = 0; j < 8; ++j) {
        int i = e0 + t + j * 512;
        if (i < e1) {
            ed[j] = dst[i];
            es[j] = src[i];
            ewv[j] = w[i];
        } else
            ed[j] = -1;
    }
    if (t < 256) h[t] = 0;
    __syncthreads();
#pragma unroll
    for (int j = 0; j < 8; ++j)
        if (ed[j] >= 0) atomicAdd(&h[ed[j] >> BKT_SHIFT], 1);
    __syncthreads();
    int v = 0;
    if (t < 256) {
        v = h[t];
        lbase[t] = v;
    }
    __syncthreads();
    for (int off = 1; off < 256; off <<= 1) {
        int u = 0;
        if (t < 256 && t >= off) u = lbase[t - off];
        __syncthreads();
        if (t < 256) lbase[t] += u;
        __syncthreads();
    }
    if (t < 256) {
        lbase[t] -= v;  // exclusive
        lcur[t] = lbase[t];
        gbase[t] = v ? atomicAdd(&gcursor[t], v) : 0;
    }
    __syncthreads();
#pragma unroll
    for (int j = 0; j < 8; ++j) {
        if (ed[j] >= 0) {
            int b = ed[j] >> BKT_SHIFT;
            int p = atomicAdd(&lcur[b], 1);
            int2 r;
            r.x = es[j] | ((ed[j] & (BKT_NODES - 1)) << 17);
            r.y = __float_as_int(ewv[j]);
            stage[p] = r;
            sb[p] = (unsigned char)b;
        }
    }
    __syncthreads();
    for (int i = t; i < n; i += 512) {
        int b = sb[i];
        binned[gbase[b] + (i - lbase[b])] = stage[i];
    }
}

// ---------------- CSR build: per-bucket counting sort, LDS-staged, streaming out ----------------

__global__ __launch_bounds__(1024) void bucket_sort(const int2* __restrict__ binned,
                                                    const int* __restrict__ bucket_off,
                                                    int2* __restrict__ sorted,
                                                    int* __restrict__ row_ptr, int N) {
    __shared__ int cnt[BKT_NODES];
    __shared__ int cur[BKT_NODES];
    __shared__ int scn[BKT_NODES];
    __shared__ int2 stage[SCAP];  // 96 KB
    int t = threadIdx.x;
    int b = blockIdx.x;
    int node0 = b << BKT_SHIFT;
    int nn = min(BKT_NODES, N - node0);
    int beg = bucket_off[b];
    int endb = bucket_off[b + 1];
    int n = endb - beg;
    if (t < BKT_NODES) cnt[t] = 0;
    __syncthreads();
    for (int i = beg + t; i < endb; i += 1024) {
        int ld = ((unsigned int)binned[i].x) >> 17;
        atomicAdd(&cnt[ld], 1);
    }
    __syncthreads();
    int v = 0;
    if (t < BKT_NODES) {
        v = cnt[t];
        scn[t] = v;
    }
    __syncthreads();
    for (int off = 1; off < BKT_NODES; off <<= 1) {
        int u = 0;
        if (t < BKT_NODES && t >= off) u = scn[t - off];
        __syncthreads();
        if (t < BKT_NODES) scn[t] += u;
        __syncthreads();
    }
    if (t < BKT_NODES) {
        int excl = scn[t] - v;
        cur[t] = excl;
        if (t < nn) row_ptr[node0 + t] = beg + excl;
    }
    __syncthreads();
    if (n <= SCAP) {
        for (int i = beg + t; i < endb; i += 1024) {
            int2 r = binned[i];
            int ld = ((unsigned int)r.x) >> 17;
            int p = atomicAdd(&cur[ld], 1);
            r.x &= 0x1FFFF;
            stage[p] = r;
        }
        __syncthreads();
        for (int i = t; i < n; i += 1024) sorted[beg + i] = stage[i];  // sequential
    } else {
        for (int i = beg + t; i < endb; i += 1024) {
            int2 r = binned[i];
            int ld = ((unsigned int)r.x) >> 17;
            int p = atomicAdd(&cur[ld], 1);
            r.x &= 0x1FFFF;
            sorted[beg + p] = r;
        }
    }
}

// ---------------- MFMA GEMM: h = relu(xb@W + b), output bf16 ----------------
// m97 pattern: 128x128 tile, BK=64, 4 waves, global_load_lds with pre-swizzled
// source; frag ds_read_b128 uses the same XOR -> conflict-free.

__global__ __launch_bounds__(256) void gemm_mfma(const unsigned short* __restrict__ xb,
                                                 const unsigned short* __restrict__ wtg,
                                                 const float* __restrict__ bias,
                                                 unsigned short* __restrict__ hbf, int N) {
    __shared__ unsigned short As[128][64];  // 16 KB
    __shared__ unsigned short Bs[128][64];  // 16 KB
    int tid = threadIdx.x;
    int wv = tid >> 6;
    int lane = tid & 63;
    int lr = lane & 15;
    int lg = lane >> 4;
    int wr = wv * 32;
    int row0 = blockIdx.x * 128;

    f32x4 acc[2][8];
#pragma unroll
    for (int m = 0; m < 2; ++m)
#pragma unroll
        for (int n = 0; n < 8; ++n) acc[m][n] = (f32x4){0.f, 0.f, 0.f, 0.f};

    int p0 = wv * 4 * 64 + lane;

    for (int kb = 0; kb < IN_DIM; kb += 64) {
#pragma unroll
        for (int i = 0; i < 4; ++i) {
            int p = p0 + i * 64;
            int r = p >> 3;
            int c = p & 7;
            int cs = (c ^ (r & 7)) * 8;
            int gr = row0 + r;
            if (gr >= N) gr = N - 1;
            const unsigned short* ga = xb + (size_t)gr * IN_DIM + kb + cs;
            __builtin_amdgcn_global_load_lds(
                (const __attribute__((address_space(1))) void*)ga,
                (__attribute__((address_space(3))) void*)((char*)&As[0][0] + (size_t)(wv * 4 + i) * 1024),
                16, 0, 0);
            const unsigned short* gb = wtg + (size_t)r * IN_DIM + kb + cs;
            __builtin_amdgcn_global_load_lds(
                (const __attribute__((address_space(1))) void*)gb,
                (__attribute__((address_space(3))) void*)((char*)&Bs[0][0] + (size_t)(wv * 4 + i) * 1024),
                16, 0, 0);
        }
        __syncthreads();

        short8 a[2][2];
#pragma unroll
        for (int m = 0; m < 2; ++m)
#pragma unroll
            for (int kk = 0; kk < 2; ++kk) {
                int r = wr + m * 16 + lr;
                int ch = kk * 4 + lg;
                a[m][kk] = *(const short8*)&As[r][((ch ^ (r & 7)) * 8)];
            }
#pragma unroll
        for (int n = 0; n < 8; ++n) {
            int cc = n * 16 + lr;
            int sw = cc & 7;
            short8 b0 = *(const short8*)&Bs[cc][(((0 * 4 + lg) ^ sw) * 8)];
            short8 b1 = *(const short8*)&Bs[cc][(((1 * 4 + lg) ^ sw) * 8)];
            acc[0][n] = __builtin_amdgcn_mfma_f32_16x16x32_bf16(a[0][0], b0, acc[0][n], 0, 0, 0);
            acc[0][n] = __builtin_amdgcn_mfma_f32_16x16x32_bf16(a[0][1], b1, acc[0][n], 0, 0, 0);
            acc[1][n] = __builtin_amdgcn_mfma_f32_16x16x32_bf16(a[1][0], b0, acc[1][n], 0, 0, 0);
            acc[1][n] = __builtin_amdgcn_mfma_f32_16x16x32_bf16(a[1][1], b1, acc[1][n], 0, 0, 0);
        }
        __syncthreads();
    }

#pragma unroll
    for (int n = 0; n < 8; ++n) {
        int c = n * 16 + lr;
        float bv = bias[c];
#pragma unroll
        for (int m = 0; m < 2; ++m) {
#pragma unroll
            for (int j = 0; j < 4; ++j) {
                int r = row0 + wr + m * 16 + lg * 4 + j;
                if (r < N) {
                    float v = fmaxf(acc[m][n][j] + bv, 0.f);
                    hbf[(size_t)r * EMB + c] = bf16rtne(v);
                }
            }
        }
    }
}

// ---------------- propagation: wave per node, readlane broadcasts, 16-deep gathers ----
// One vector load grabs up to 64 edge records into registers; readlane
// broadcasts src/w (register-resident, no memory latency). 16 gathers in
// flight per batch -> ~22KB/CU in flight (2x round-11's 8-deep).

template <int OUTBF>
__global__ __launch_bounds__(256) void prop_g(const unsigned int* __restrict__ hin,
                                              void* __restrict__ hout,
                                              const int* __restrict__ rp,
                                              const int2* __restrict__ rec, int N) {
    int wvid = threadIdx.x >> 6;
    int lane = threadIdx.x & 63;
    int node = blockIdx.x * 4 + wvid;
    if (node >= N) return;
    int beg = __builtin_amdgcn_readfirstlane(rp[node]);
    int end = __builtin_amdgcn_readfirstlane(rp[node + 1]);
    float ax = 0.f, ay = 0.f;
    for (int c0 = beg; c0 < end; c0 += 64) {
        int cnt = end - c0;
        if (cnt > 64) cnt = 64;
        int li = lane < cnt ? lane : 0;
        int2 r = rec[c0 + li];
        for (int jb = 0; jb < cnt; jb += 16) {
            int ssrc[16];
            float sw[16];
#pragma unroll
            for (int k = 0; k < 16; ++k) {
                int jj = jb + k;
                int jc = jj < cnt ? jj : 0;
                ssrc[k] = __builtin_amdgcn_readlane(r.x, jc);
                float wv = __uint_as_float((unsigned int)__builtin_amdgcn_readlane(r.y, jc));
                sw[k] = (jj < cnt) ? wv : 0.f;
            }
            unsigned int g[16];
#pragma unroll
            for (int k = 0; k < 16; ++k) g[k] = hin[(size_t)ssrc[k] * 64 + lane];
#pragma unroll
            for (int k = 0; k < 16; ++k) {
                ax = fmaf(sw[k], __uint_as_float(g[k] << 16), ax);
                ay = fmaf(sw[k], __uint_as_float(g[k] & 0xffff0000u), ay);
            }
        }
    }
    if (OUTBF) {
        ((unsigned int*)hout)[(size_t)node * 64 + lane] = packbf2(ax, ay);
    } else {
        float2 o;
        o.x = ax;
        o.y = ay;
        ((float2*)hout)[(size_t)node * 64 + lane] = o;
    }
}

// ---------------- launch ----------------

extern "C" void kernel_launch(void* const* d_in, const int* in_sizes, int n_in,
                              void* d_out, int out_size, void* d_ws, size_t ws_size,
                              hipStream_t stream) {
    const float* x = (const float*)d_in[0];
    const float* W = (const float*)d_in[1];
    const float* b = (const float*)d_in[2];
    const int* esrc = (const int*)d_in[3];
    const int* edst = (const int*)d_in[4];
    const float* ew = (const float*)d_in[5];
    int N = in_sizes[0] / IN_DIM;
    int E = in_sizes[3];
    int NB = (N + BKT_NODES - 1) >> BKT_SHIFT;  // 196

    char* p = (char*)d_ws;
    auto alloc = [&](size_t bytes) -> void* {
        void* r = (void*)p;
        p += (bytes + 255) & ~(size_t)255;
        return r;
    };
    unsigned short* hbf = (unsigned short*)alloc((size_t)N * EMB * 2);
    unsigned short* h1bf = (unsigned short*)alloc((size_t)N * EMB * 2);
    unsigned short* wtg = (unsigned short*)alloc((size_t)IN_DIM * EMB * 2);
    unsigned short* xbf = (unsigned short*)alloc((size_t)N * IN_DIM * 2);
    int* ghist = (int*)alloc(256 * 4);
    int* gcursor = (int*)alloc(256 * 4);
    int* bucket_off = (int*)alloc((size_t)(NB + 1) * 4);
    int* row_ptr = (int*)alloc((size_t)(N + 1) * 4);
    int2* binned = (int2*)alloc((size_t)E * 8);
    int2* sorted = (int2*)alloc((size_t)E * 8);

    hipMemsetAsync(ghist, 0, 256 * 4, stream);
    prep<<<2048, 256, 0, stream>>>(W, wtg, x, xbf, N * IN_DIM / 8, edst, ghist, E);
    bucket_scan<<<1, 256, 0, stream>>>(ghist, bucket_off, gcursor, row_ptr, NB, N, E);
    bin_scatter<<<(E + BINE - 1) / BINE, 512, 0, stream>>>(esrc, edst, ew, gcursor, binned, E);
    bucket_sort<<<NB, 1024, 0, stream>>>(binned, bucket_off, sorted, row_ptr, N);

    gemm_mfma<<<(N + 127) / 128, 256, 0, stream>>>(xbf, wtg, b, hbf, N);
    prop_g<1><<<(N + 3) / 4, 256, 0, stream>>>((const unsigned int*)hbf, h1bf, row_ptr, sorted, N);
    prop_g<0><<<(N + 3) / 4, 256, 0, stream>>>((const unsigned int*)h1bf, d_out, row_ptr, sorted, N);
}

// Round 15
// 237.154 us; speedup vs baseline: 1.1188x; 1.0292x over previous
//
#include <hip/hip_runtime.h>

#define IN_DIM 256
#define EMB 128
// bucket = dst >> 9 (512 nodes per bucket). Requires N <= 131072 (src packed in 17 bits).
#define BKT_SHIFT 9
#define BKT_NODES 512
#define BINE 4096       // edges per bin_scatter block
#define SCAP 12288      // bucket_sort LDS staging capacity (mean ~8163, huge margin)

typedef __attribute__((ext_vector_type(8))) short short8;
typedef __attribute__((ext_vector_type(4))) float f32x4;

__device__ __forceinline__ unsigned short bf16rtne(float f) {
    unsigned int u = __float_as_uint(f);
    return (unsigned short)((u + 0x7fffu + ((u >> 16) & 1u)) >> 16);
}

__device__ __forceinline__ unsigned int packbf2(float lo, float hi) {
    return ((unsigned int)bf16rtne(hi) << 16) | (unsigned int)bf16rtne(lo);
}

// packed f32x8 -> bf16x8 via native cvt_pk (RNE)
__device__ __forceinline__ short8 pack8(float4 f0, float4 f1) {
    union { uint4 u; short8 s; } U;
    asm("v_cvt_pk_bf16_f32 %0, %1, %2" : "=v"(U.u.x) : "v"(f0.x), "v"(f0.y));
    asm("v_cvt_pk_bf16_f32 %0, %1, %2" : "=v"(U.u.y) : "v"(f0.z), "v"(f0.w));
    asm("v_cvt_pk_bf16_f32 %0, %1, %2" : "=v"(U.u.z) : "v"(f1.x), "v"(f1.y));
    asm("v_cvt_pk_bf16_f32 %0, %1, %2" : "=v"(U.u.w) : "v"(f1.z), "v"(f1.w));
    return U.s;
}

// ---------------- fused prep: wt_cast + x_cast (MLP-deep) + bucket_hist ----------------

__global__ __launch_bounds__(256) void prep(const float* __restrict__ W,
                                            unsigned short* __restrict__ wtg,
                                            const float* __restrict__ x,
                                            unsigned short* __restrict__ xb, int total8,
                                            const int* __restrict__ dst,
                                            int* __restrict__ ghist, int E) {
    int t = threadIdx.x;
    int gsz = gridDim.x * 256;
    int gid = blockIdx.x * 256 + t;
    // W^T cast (tiny)
    for (int i = gid; i < IN_DIM * EMB; i += gsz) {
        int c = i & 127;
        int k = i >> 7;
        wtg[c * 256 + k] = bf16rtne(W[(size_t)k * 128 + c]);
    }
    // x cast: groups of 1024 chunks/block; 4 chunks/thread, all loads issued first
    int ngrp = (total8 + 1023) >> 10;
    for (int g = blockIdx.x; g < ngrp; g += gridDim.x) {
        int i0 = (g << 10) + t;
        float4 f[8];
        bool ok[4];
#pragma unroll
        for (int j = 0; j < 4; ++j) {
            int i = i0 + j * 256;
            ok[j] = i < total8;
            if (ok[j]) {
                const float4* s = (const float4*)(x + (size_t)i * 8);
                f[2 * j] = s[0];
                f[2 * j + 1] = s[1];
            }
        }
#pragma unroll
        for (int j = 0; j < 4; ++j) {
            int i = i0 + j * 256;
            if (ok[j]) *(short8*)(xb + (size_t)i * 8) = pack8(f[2 * j], f[2 * j + 1]);
        }
    }
    // bucket histogram: int4 vectorized dst reads
    __shared__ int h[256];
    h[t] = 0;
    __syncthreads();
    int nE4 = E >> 2;
    for (int i = gid; i < nE4; i += gsz) {
        int4 d = ((const int4*)dst)[i];
        atomicAdd(&h[d.x >> BKT_SHIFT], 1);
        atomicAdd(&h[d.y >> BKT_SHIFT], 1);
        atomicAdd(&h[d.z >> BKT_SHIFT], 1);
        atomicAdd(&h[d.w >> BKT_SHIFT], 1);
    }
    for (int i = (nE4 << 2) + gid; i < E; i += gsz) atomicAdd(&h[dst[i] >> BKT_SHIFT], 1);
    __syncthreads();
    if (h[t]) atomicAdd(&ghist[t], h[t]);
}

// single block: exclusive scan of bucket counts -> bucket_off, gcursor
__global__ __launch_bounds__(256) void bucket_scan(const int* __restrict__ ghist,
                                                   int* __restrict__ bucket_off,
                                                   int* __restrict__ gcursor,
                                                   int* __restrict__ row_ptr,
                                                   int NB, int N, int E) {
    __shared__ int s[256];
    int t = threadIdx.x;
    int v = (t < NB) ? ghist[t] : 0;
    s[t] = v;
    __syncthreads();
    for (int off = 1; off < 256; off <<= 1) {
        int u = (t >= off) ? s[t - off] : 0;
        __syncthreads();
        s[t] += u;
        __syncthreads();
    }
    int excl = s[t] - v;
    if (t < NB) {
        bucket_off[t] = excl;
        gcursor[t] = excl;
    }
    if (t == 0) {
        bucket_off[NB] = E;
        row_ptr[N] = E;
    }
}

// ---------------- CSR build: bin edges by bucket, LDS-staged, streaming out ----------------

__global__ __launch_bounds__(512) void bin_scatter(const int* __restrict__ src,
                                                   const int* __restrict__ dst,
                                                   const float* __restrict__ w,
                                                   int* __restrict__ gcursor,
                                                   int2* __restrict__ binned, int E) {
    __shared__ int h[256];
    __shared__ int lbase[256];
    __shared__ int gbase[256];
    __shared__ int lcur[256];
    __shared__ int2 stage[BINE];         // 32 KB
    __shared__ unsigned char sb[BINE];   // slot -> bucket, 4 KB
    int t = threadIdx.x;
    int e0 = blockIdx.x * BINE;
    int e1 = min(E, e0 + BINE);
    int n = e1 - e0;

    int ed[8], es[8];
    float ewv[8];
#pragma unroll
    for (int j = 0; j < 8; ++j) {
        int i = e0 + t + j * 512;
        if (i < e1) {
            ed[j] = dst[i];
            es[j] = src[i];
            ewv[j] = w[i];
        } else
            ed[j] = -1;
    }
    if (t < 256) h[t] = 0;
    __syncthreads();
#pragma unroll
    for (int j = 0; j < 8; ++j)
        if (ed[j] >= 0) atomicAdd(&h[ed[j] >> BKT_SHIFT], 1);
    __syncthreads();
    int v = 0;
    if (t < 256) {
        v = h[t];
        lbase[t] = v;
    }
    __syncthreads();
    for (int off = 1; off < 256; off <<= 1) {
        int u = 0;
        if (t < 256 && t >= off) u = lbase[t - off];
        __syncthreads();
        if (t < 256) lbase[t] += u;
        __syncthreads();
    }
    if (t < 256) {
        lbase[t] -= v;  // exclusive
        lcur[t] = lbase[t];
        gbase[t] = v ? atomicAdd(&gcursor[t], v) : 0;
    }
    __syncthreads();
#pragma unroll
    for (int j = 0; j < 8; ++j) {
        if (ed[j] >= 0) {
            int b = ed[j] >> BKT_SHIFT;
            int p = atomicAdd(&lcur[b], 1);
            int2 r;
            r.x = es[j] | ((ed[j] & (BKT_NODES - 1)) << 17);
            r.y = __float_as_int(ewv[j]);
            stage[p] = r;
            sb[p] = (unsigned char)b;
        }
    }
    __syncthreads();
    for (int i = t; i < n; i += 512) {
        int b = sb[i];
        binned[gbase[b] + (i - lbase[b])] = stage[i];
    }
}

// ---------------- CSR build: per-bucket counting sort, LDS-staged, streaming out ----------------

__global__ __launch_bounds__(1024) void bucket_sort(const int2* __restrict__ binned,
                                                    const int* __restrict__ bucket_off,
                                                    int2* __restrict__ sorted,
                                                    int* __restrict__ row_ptr, int N) {
    __shared__ int cnt[BKT_NODES];
    __shared__ int cur[BKT_NODES];
    __shared__ int scn[BKT_NODES];
    __shared__ int2 stage[SCAP];  // 96 KB
    int t = threadIdx.x;
    int b = blockIdx.x;
    int node0 = b << BKT_SHIFT;
    int nn = min(BKT_NODES, N - node0);
    int beg = bucket_off[b];
    int endb = bucket_off[b + 1];
    int n = endb - beg;
    if (t < BKT_NODES) cnt[t] = 0;
    __syncthreads();
    for (int i = beg + t; i < endb; i += 1024) {
        int ld = ((unsigned int)binned[i].x) >> 17;
        atomicAdd(&cnt[ld], 1);
    }
    __syncthreads();
    int v = 0;
    if (t < BKT_NODES) {
        v = cnt[t];
        scn[t] = v;
    }
    __syncthreads();
    for (int off = 1; off < BKT_NODES; off <<= 1) {
        int u = 0;
        if (t < BKT_NODES && t >= off) u = scn[t - off];
        __syncthreads();
        if (t < BKT_NODES) scn[t] += u;
        __syncthreads();
    }
    if (t < BKT_NODES) {
        int excl = scn[t] - v;
        cur[t] = excl;
        if (t < nn) row_ptr[node0 + t] = beg + excl;
    }
    __syncthreads();
    if (n <= SCAP) {
        for (int i = beg + t; i < endb; i += 1024) {
            int2 r = binned[i];
            int ld = ((unsigned int)r.x) >> 17;
            int p = atomicAdd(&cur[ld], 1);
            r.x &= 0x1FFFF;
            stage[p] = r;
        }
        __syncthreads();
        for (int i = t; i < n; i += 1024) sorted[beg + i] = stage[i];  // sequential
    } else {
        for (int i = beg + t; i < endb; i += 1024) {
            int2 r = binned[i];
            int ld = ((unsigned int)r.x) >> 17;
            int p = atomicAdd(&cur[ld], 1);
            r.x &= 0x1FFFF;
            sorted[beg + p] = r;
        }
    }
}

// ---------------- MFMA GEMM: h = relu(xb@W + b), output bf16 ----------------
// m97 pattern: 128x128 tile, BK=64, 4 waves, global_load_lds with pre-swizzled
// source; frag ds_read_b128 uses the same XOR -> conflict-free.

__global__ __launch_bounds__(256) void gemm_mfma(const unsigned short* __restrict__ xb,
                                                 const unsigned short* __restrict__ wtg,
                                                 const float* __restrict__ bias,
                                                 unsigned short* __restrict__ hbf, int N) {
    __shared__ unsigned short As[128][64];  // 16 KB
    __shared__ unsigned short Bs[128][64];  // 16 KB
    int tid = threadIdx.x;
    int wv = tid >> 6;
    int lane = tid & 63;
    int lr = lane & 15;
    int lg = lane >> 4;
    int wr = wv * 32;
    int row0 = blockIdx.x * 128;

    f32x4 acc[2][8];
#pragma unroll
    for (int m = 0; m < 2; ++m)
#pragma unroll
        for (int n = 0; n < 8; ++n) acc[m][n] = (f32x4){0.f, 0.f, 0.f, 0.f};

    int p0 = wv * 4 * 64 + lane;

    for (int kb = 0; kb < IN_DIM; kb += 64) {
#pragma unroll
        for (int i = 0; i < 4; ++i) {
            int p = p0 + i * 64;
            int r = p >> 3;
            int c = p & 7;
            int cs = (c ^ (r & 7)) * 8;
            int gr = row0 + r;
            if (gr >= N) gr = N - 1;
            const unsigned short* ga = xb + (size_t)gr * IN_DIM + kb + cs;
            __builtin_amdgcn_global_load_lds(
                (const __attribute__((address_space(1))) void*)ga,
                (__attribute__((address_space(3))) void*)((char*)&As[0][0] + (size_t)(wv * 4 + i) * 1024),
                16, 0, 0);
            const unsigned short* gb = wtg + (size_t)r * IN_DIM + kb + cs;
            __builtin_amdgcn_global_load_lds(
                (const __attribute__((address_space(1))) void*)gb,
                (__attribute__((address_space(3))) void*)((char*)&Bs[0][0] + (size_t)(wv * 4 + i) * 1024),
                16, 0, 0);
        }
        __syncthreads();

        short8 a[2][2];
#pragma unroll
        for (int m = 0; m < 2; ++m)
#pragma unroll
            for (int kk = 0; kk < 2; ++kk) {
                int r = wr + m * 16 + lr;
                int ch = kk * 4 + lg;
                a[m][kk] = *(const short8*)&As[r][((ch ^ (r & 7)) * 8)];
            }
#pragma unroll
        for (int n = 0; n < 8; ++n) {
            int cc = n * 16 + lr;
            int sw = cc & 7;
            short8 b0 = *(const short8*)&Bs[cc][(((0 * 4 + lg) ^ sw) * 8)];
            short8 b1 = *(const short8*)&Bs[cc][(((1 * 4 + lg) ^ sw) * 8)];
            acc[0][n] = __builtin_amdgcn_mfma_f32_16x16x32_bf16(a[0][0], b0, acc[0][n], 0, 0, 0);
            acc[0][n] = __builtin_amdgcn_mfma_f32_16x16x32_bf16(a[0][1], b1, acc[0][n], 0, 0, 0);
            acc[1][n] = __builtin_amdgcn_mfma_f32_16x16x32_bf16(a[1][0], b0, acc[1][n], 0, 0, 0);
            acc[1][n] = __builtin_amdgcn_mfma_f32_16x16x32_bf16(a[1][1], b1, acc[1][n], 0, 0, 0);
        }
        __syncthreads();
    }

#pragma unroll
    for (int n = 0; n < 8; ++n) {
        int c = n * 16 + lr;
        float bv = bias[c];
#pragma unroll
        for (int m = 0; m < 2; ++m) {
#pragma unroll
            for (int j = 0; j < 4; ++j) {
                int r = row0 + wr + m * 16 + lg * 4 + j;
                if (r < N) {
                    float v = fmaxf(acc[m][n][j] + bv, 0.f);
                    hbf[(size_t)r * EMB + c] = bf16rtne(v);
                }
            }
        }
    }
}

// ---------------- propagation: wave per node, readlane broadcasts, 16-deep gathers ----

template <int OUTBF>
__global__ __launch_bounds__(256) void prop_g(const unsigned int* __restrict__ hin,
                                              void* __restrict__ hout,
                                              const int* __restrict__ rp,
                                              const int2* __restrict__ rec, int N) {
    int wvid = threadIdx.x >> 6;
    int lane = threadIdx.x & 63;
    int node = blockIdx.x * 4 + wvid;
    if (node >= N) return;
    int beg = __builtin_amdgcn_readfirstlane(rp[node]);
    int end = __builtin_amdgcn_readfirstlane(rp[node + 1]);
    float ax = 0.f, ay = 0.f;
    for (int c0 = beg; c0 < end; c0 += 64) {
        int cnt = end - c0;
        if (cnt > 64) cnt = 64;
        int li = lane < cnt ? lane : 0;
        int2 r = rec[c0 + li];
        for (int jb = 0; jb < cnt; jb += 16) {
            int ssrc[16];
            float sw[16];
#pragma unroll
            for (int k = 0; k < 16; ++k) {
                int jj = jb + k;
                int jc = jj < cnt ? jj : 0;
                ssrc[k] = __builtin_amdgcn_readlane(r.x, jc);
                float wv = __uint_as_float((unsigned int)__builtin_amdgcn_readlane(r.y, jc));
                sw[k] = (jj < cnt) ? wv : 0.f;
            }
            unsigned int g[16];
#pragma unroll
            for (int k = 0; k < 16; ++k) g[k] = hin[(size_t)ssrc[k] * 64 + lane];
#pragma unroll
            for (int k = 0; k < 16; ++k) {
                ax = fmaf(sw[k], __uint_as_float(g[k] << 16), ax);
                ay = fmaf(sw[k], __uint_as_float(g[k] & 0xffff0000u), ay);
            }
        }
    }
    if (OUTBF) {
        ((unsigned int*)hout)[(size_t)node * 64 + lane] = packbf2(ax, ay);
    } else {
        float2 o;
        o.x = ax;
        o.y = ay;
        ((float2*)hout)[(size_t)node * 64 + lane] = o;
    }
}

// ---------------- launch ----------------

extern "C" void kernel_launch(void* const* d_in, const int* in_sizes, int n_in,
                              void* d_out, int out_size, void* d_ws, size_t ws_size,
                              hipStream_t stream) {
    const float* x = (const float*)d_in[0];
    const float* W = (const float*)d_in[1];
    const float* b = (const float*)d_in[2];
    const int* esrc = (const int*)d_in[3];
    const int* edst = (const int*)d_in[4];
    const float* ew = (const float*)d_in[5];
    int N = in_sizes[0] / IN_DIM;
    int E = in_sizes[3];
    int NB = (N + BKT_NODES - 1) >> BKT_SHIFT;  // 196

    char* p = (char*)d_ws;
    auto alloc = [&](size_t bytes) -> void* {
        void* r = (void*)p;
        p += (bytes + 255) & ~(size_t)255;
        return r;
    };
    unsigned short* hbf = (unsigned short*)alloc((size_t)N * EMB * 2);
    unsigned short* h1bf = (unsigned short*)alloc((size_t)N * EMB * 2);
    unsigned short* wtg = (unsigned short*)alloc((size_t)IN_DIM * EMB * 2);
    unsigned short* xbf = (unsigned short*)alloc((size_t)N * IN_DIM * 2);
    int* ghist = (int*)alloc(256 * 4);
    int* gcursor = (int*)alloc(256 * 4);
    int* bucket_off = (int*)alloc((size_t)(NB + 1) * 4);
    int* row_ptr = (int*)alloc((size_t)(N + 1) * 4);
    int2* binned = (int2*)alloc((size_t)E * 8);
    int2* sorted = (int2*)alloc((size_t)E * 8);

    hipMemsetAsync(ghist, 0, 256 * 4, stream);
    prep<<<2048, 256, 0, stream>>>(W, wtg, x, xbf, N * IN_DIM / 8, edst, ghist, E);
    bucket_scan<<<1, 256, 0, stream>>>(ghist, bucket_off, gcursor, row_ptr, NB, N, E);
    bin_scatter<<<(E + BINE - 1) / BINE, 512, 0, stream>>>(esrc, edst, ew, gcursor, binned, E);
    bucket_sort<<<NB, 1024, 0, stream>>>(binned, bucket_off, sorted, row_ptr, N);

    gemm_mfma<<<(N + 127) / 128, 256, 0, stream>>>(xbf, wtg, b, hbf, N);
    prop_g<1><<<(N + 3) / 4, 256, 0, stream>>>((const unsigned int*)hbf, h1bf, row_ptr, sorted, N);
    prop_g<0><<<(N + 3) / 4, 256, 0, stream>>>((const unsigned int*)h1bf, d_out, row_ptr, sorted, N);
}

// Round 16
// 230.345 us; speedup vs baseline: 1.1519x; 1.0296x over previous
//
#include <hip/hip_runtime.h>

#define IN_DIM 256
#define EMB 128
// bucket = dst >> 9 (512 nodes per bucket). Requires N <= 131072 (src packed in 17 bits).
#define BKT_SHIFT 9
#define BKT_NODES 512
#define BINE 4096       // edges per bin_scatter block
#define SCAP 12288      // bucket_sort LDS staging capacity (mean ~8163, huge margin)

typedef __attribute__((ext_vector_type(8))) short short8;
typedef __attribute__((ext_vector_type(4))) float f32x4;

__device__ __forceinline__ unsigned short bf16rtne(float f) {
    unsigned int u = __float_as_uint(f);
    return (unsigned short)((u + 0x7fffu + ((u >> 16) & 1u)) >> 16);
}

__device__ __forceinline__ unsigned int packbf2(float lo, float hi) {
    return ((unsigned int)bf16rtne(hi) << 16) | (unsigned int)bf16rtne(lo);
}

// packed f32x8 -> bf16x8 via native cvt_pk (RNE)
__device__ __forceinline__ short8 pack8(float4 f0, float4 f1) {
    union { uint4 u; short8 s; } U;
    asm("v_cvt_pk_bf16_f32 %0, %1, %2" : "=v"(U.u.x) : "v"(f0.x), "v"(f0.y));
    asm("v_cvt_pk_bf16_f32 %0, %1, %2" : "=v"(U.u.y) : "v"(f0.z), "v"(f0.w));
    asm("v_cvt_pk_bf16_f32 %0, %1, %2" : "=v"(U.u.z) : "v"(f1.x), "v"(f1.y));
    asm("v_cvt_pk_bf16_f32 %0, %1, %2" : "=v"(U.u.w) : "v"(f1.z), "v"(f1.w));
    return U.s;
}

// ---------------- fused prep: wt_cast + x_cast (branch-free MLP) + bucket_hist ----------------

__global__ __launch_bounds__(256) void prep(const float* __restrict__ W,
                                            unsigned short* __restrict__ wtg,
                                            const float* __restrict__ x,
                                            unsigned short* __restrict__ xb, int total8,
                                            const int* __restrict__ dst,
                                            int* __restrict__ ghist, int E) {
    int t = threadIdx.x;
    int gsz = gridDim.x * 256;
    int gid = blockIdx.x * 256 + t;
    // W^T cast (tiny)
    for (int i = gid; i < IN_DIM * EMB; i += gsz) {
        int c = i & 127;
        int k = i >> 7;
        wtg[c * 256 + k] = bf16rtne(W[(size_t)k * 128 + c]);
    }
    // x cast: full 1024-chunk groups, BRANCH-FREE body (8 loads in flight/thread)
    int full = total8 >> 10;  // groups with no bounds risk
    for (int g = blockIdx.x; g < full; g += gridDim.x) {
        int i0 = (g << 10) + t;
        float4 f[8];
#pragma unroll
        for (int j = 0; j < 4; ++j) {
            const float4* s = (const float4*)(x + (size_t)(i0 + j * 256) * 8);
            f[2 * j] = s[0];
            f[2 * j + 1] = s[1];
        }
#pragma unroll
        for (int j = 0; j < 4; ++j)
            *(short8*)(xb + (size_t)(i0 + j * 256) * 8) = pack8(f[2 * j], f[2 * j + 1]);
    }
    // tail chunks (none when total8 % 1024 == 0)
    for (int i = (full << 10) + gid; i < total8; i += gsz) {
        const float4* s = (const float4*)(x + (size_t)i * 8);
        *(short8*)(xb + (size_t)i * 8) = pack8(s[0], s[1]);
    }
    // bucket histogram: int4 vectorized dst reads
    __shared__ int h[256];
    h[t] = 0;
    __syncthreads();
    int nE4 = E >> 2;
    for (int i = gid; i < nE4; i += gsz) {
        int4 d = ((const int4*)dst)[i];
        atomicAdd(&h[d.x >> BKT_SHIFT], 1);
        atomicAdd(&h[d.y >> BKT_SHIFT], 1);
        atomicAdd(&h[d.z >> BKT_SHIFT], 1);
        atomicAdd(&h[d.w >> BKT_SHIFT], 1);
    }
    for (int i = (nE4 << 2) + gid; i < E; i += gsz) atomicAdd(&h[dst[i] >> BKT_SHIFT], 1);
    __syncthreads();
    if (h[t]) atomicAdd(&ghist[t], h[t]);
}

// single block: exclusive scan of bucket counts -> bucket_off, gcursor
__global__ __launch_bounds__(256) void bucket_scan(const int* __restrict__ ghist,
                                                   int* __restrict__ bucket_off,
                                                   int* __restrict__ gcursor,
                                                   int* __restrict__ row_ptr,
                                                   int NB, int N, int E) {
    __shared__ int s[256];
    int t = threadIdx.x;
    int v = (t < NB) ? ghist[t] : 0;
    s[t] = v;
    __syncthreads();
    for (int off = 1; off < 256; off <<= 1) {
        int u = (t >= off) ? s[t - off] : 0;
        __syncthreads();
        s[t] += u;
        __syncthreads();
    }
    int excl = s[t] - v;
    if (t < NB) {
        bucket_off[t] = excl;
        gcursor[t] = excl;
    }
    if (t == 0) {
        bucket_off[NB] = E;
        row_ptr[N] = E;
    }
}

// ---------------- CSR build: bin edges by bucket, LDS-staged, streaming out ----------------

__global__ __launch_bounds__(512) void bin_scatter(const int* __restrict__ src,
                                                   const int* __restrict__ dst,
                                                   const float* __restrict__ w,
                                                   int* __restrict__ gcursor,
                                                   int2* __restrict__ binned, int E) {
    __shared__ int h[256];
    __shared__ int lbase[256];
    __shared__ int gbase[256];
    __shared__ int lcur[256];
    __shared__ int2 stage[BINE];         // 32 KB
    __shared__ unsigned char sb[BINE];   // slot -> bucket, 4 KB
    int t = threadIdx.x;
    int e0 = blockIdx.x * BINE;
    int e1 = min(E, e0 + BINE);
    int n = e1 - e0;

    int ed[8], es[8];
    float ewv[8];
#pragma unroll
    for (int j = 0; j < 8; ++j) {
        int i = e0 + t + j * 512;
        if (i < e1) {
            ed[j] = dst[i];
            es[j] = src[i];
            ewv[j] = w[i];
        } else
            ed[j] = -1;
    }
    if (t < 256) h[t] = 0;
    __syncthreads();
#pragma unroll
    for (int j = 0; j < 8; ++j)
        if (ed[j] >= 0) atomicAdd(&h[ed[j] >> BKT_SHIFT], 1);
    __syncthreads();
    int v = 0;
    if (t < 256) {
        v = h[t];
        lbase[t] = v;
    }
    __syncthreads();
    for (int off = 1; off < 256; off <<= 1) {
        int u = 0;
        if (t < 256 && t >= off) u = lbase[t - off];
        __syncthreads();
        if (t < 256) lbase[t] += u;
        __syncthreads();
    }
    if (t < 256) {
        lbase[t] -= v;  // exclusive
        lcur[t] = lbase[t];
        gbase[t] = v ? atomicAdd(&gcursor[t], v) : 0;
    }
    __syncthreads();
#pragma unroll
    for (int j = 0; j < 8; ++j) {
        if (ed[j] >= 0) {
            int b = ed[j] >> BKT_SHIFT;
            int p = atomicAdd(&lcur[b], 1);
            int2 r;
            r.x = es[j] | ((ed[j] & (BKT_NODES - 1)) << 17);
            r.y = __float_as_int(ewv[j]);
            stage[p] = r;
            sb[p] = (unsigned char)b;
        }
    }
    __syncthreads();
    for (int i = t; i < n; i += 512) {
        int b = sb[i];
        binned[gbase[b] + (i - lbase[b])] = stage[i];
    }
}

// ---------------- CSR build: per-bucket counting sort, LDS-staged, streaming out ----------------

__global__ __launch_bounds__(1024) void bucket_sort(const int2* __restrict__ binned,
                                                    const int* __restrict__ bucket_off,
                                                    int2* __restrict__ sorted,
                                                    int* __restrict__ row_ptr, int N) {
    __shared__ int cnt[BKT_NODES];
    __shared__ int cur[BKT_NODES];
    __shared__ int scn[BKT_NODES];
    __shared__ int2 stage[SCAP];  // 96 KB
    int t = threadIdx.x;
    int b = blockIdx.x;
    int node0 = b << BKT_SHIFT;
    int nn = min(BKT_NODES, N - node0);
    int beg = bucket_off[b];
    int endb = bucket_off[b + 1];
    int n = endb - beg;
    if (t < BKT_NODES) cnt[t] = 0;
    __syncthreads();
    for (int i = beg + t; i < endb; i += 1024) {
        int ld = ((unsigned int)binned[i].x) >> 17;
        atomicAdd(&cnt[ld], 1);
    }
    __syncthreads();
    int v = 0;
    if (t < BKT_NODES) {
        v = cnt[t];
        scn[t] = v;
    }
    __syncthreads();
    for (int off = 1; off < BKT_NODES; off <<= 1) {
        int u = 0;
        if (t < BKT_NODES && t >= off) u = scn[t - off];
        __syncthreads();
        if (t < BKT_NODES) scn[t] += u;
        __syncthreads();
    }
    if (t < BKT_NODES) {
        int excl = scn[t] - v;
        cur[t] = excl;
        if (t < nn) row_ptr[node0 + t] = beg + excl;
    }
    __syncthreads();
    if (n <= SCAP) {
        for (int i = beg + t; i < endb; i += 1024) {
            int2 r = binned[i];
            int ld = ((unsigned int)r.x) >> 17;
            int p = atomicAdd(&cur[ld], 1);
            r.x &= 0x1FFFF;
            stage[p] = r;
        }
        __syncthreads();
        for (int i = t; i < n; i += 1024) sorted[beg + i] = stage[i];  // sequential
    } else {
        for (int i = beg + t; i < endb; i += 1024) {
            int2 r = binned[i];
            int ld = ((unsigned int)r.x) >> 17;
            int p = atomicAdd(&cur[ld], 1);
            r.x &= 0x1FFFF;
            sorted[beg + p] = r;
        }
    }
}

// ---------------- MFMA GEMM: h = relu(xb@W + b), output bf16 ----------------
// m97 pattern: 128x128 tile, BK=64, 4 waves, global_load_lds with pre-swizzled
// source; frag ds_read_b128 uses the same XOR -> conflict-free.

__global__ __launch_bounds__(256) void gemm_mfma(const unsigned short* __restrict__ xb,
                                                 const unsigned short* __restrict__ wtg,
                                                 const float* __restrict__ bias,
                                                 unsigned short* __restrict__ hbf, int N) {
    __shared__ unsigned short As[128][64];  // 16 KB
    __shared__ unsigned short Bs[128][64];  // 16 KB
    int tid = threadIdx.x;
    int wv = tid >> 6;
    int lane = tid & 63;
    int lr = lane & 15;
    int lg = lane >> 4;
    int wr = wv * 32;
    int row0 = blockIdx.x * 128;

    f32x4 acc[2][8];
#pragma unroll
    for (int m = 0; m < 2; ++m)
#pragma unroll
        for (int n = 0; n < 8; ++n) acc[m][n] = (f32x4){0.f, 0.f, 0.f, 0.f};

    int p0 = wv * 4 * 64 + lane;

    for (int kb = 0; kb < IN_DIM; kb += 64) {
#pragma unroll
        for (int i = 0; i < 4; ++i) {
            int p = p0 + i * 64;
            int r = p >> 3;
            int c = p & 7;
            int cs = (c ^ (r & 7)) * 8;
            int gr = row0 + r;
            if (gr >= N) gr = N - 1;
            const unsigned short* ga = xb + (size_t)gr * IN_DIM + kb + cs;
            __builtin_amdgcn_global_load_lds(
                (const __attribute__((address_space(1))) void*)ga,
                (__attribute__((address_space(3))) void*)((char*)&As[0][0] + (size_t)(wv * 4 + i) * 1024),
                16, 0, 0);
            const unsigned short* gb = wtg + (size_t)r * IN_DIM + kb + cs;
            __builtin_amdgcn_global_load_lds(
                (const __attribute__((address_space(1))) void*)gb,
                (__attribute__((address_space(3))) void*)((char*)&Bs[0][0] + (size_t)(wv * 4 + i) * 1024),
                16, 0, 0);
        }
        __syncthreads();

        short8 a[2][2];
#pragma unroll
        for (int m = 0; m < 2; ++m)
#pragma unroll
            for (int kk = 0; kk < 2; ++kk) {
                int r = wr + m * 16 + lr;
                int ch = kk * 4 + lg;
                a[m][kk] = *(const short8*)&As[r][((ch ^ (r & 7)) * 8)];
            }
#pragma unroll
        for (int n = 0; n < 8; ++n) {
            int cc = n * 16 + lr;
            int sw = cc & 7;
            short8 b0 = *(const short8*)&Bs[cc][(((0 * 4 + lg) ^ sw) * 8)];
            short8 b1 = *(const short8*)&Bs[cc][(((1 * 4 + lg) ^ sw) * 8)];
            acc[0][n] = __builtin_amdgcn_mfma_f32_16x16x32_bf16(a[0][0], b0, acc[0][n], 0, 0, 0);
            acc[0][n] = __builtin_amdgcn_mfma_f32_16x16x32_bf16(a[0][1], b1, acc[0][n], 0, 0, 0);
            acc[1][n] = __builtin_amdgcn_mfma_f32_16x16x32_bf16(a[1][0], b0, acc[1][n], 0, 0, 0);
            acc[1][n] = __builtin_amdgcn_mfma_f32_16x16x32_bf16(a[1][1], b1, acc[1][n], 0, 0, 0);
        }
        __syncthreads();
    }

#pragma unroll
    for (int n = 0; n < 8; ++n) {
        int c = n * 16 + lr;
        float bv = bias[c];
#pragma unroll
        for (int m = 0; m < 2; ++m) {
#pragma unroll
            for (int j = 0; j < 4; ++j) {
                int r = row0 + wr + m * 16 + lg * 4 + j;
                if (r < N) {
                    float v = fmaxf(acc[m][n][j] + bv, 0.f);
                    hbf[(size_t)r * EMB + c] = bf16rtne(v);
                }
            }
        }
    }
}

// ---------------- propagation: wave per node, readlane broadcasts, 16-deep gathers ----

template <int OUTBF>
__global__ __launch_bounds__(256) void prop_g(const unsigned int* __restrict__ hin,
                                              void* __restrict__ hout,
                                              const int* __restrict__ rp,
                                              const int2* __restrict__ rec, int N) {
    int wvid = threadIdx.x >> 6;
    int lane = threadIdx.x & 63;
    int node = blockIdx.x * 4 + wvid;
    if (node >= N) return;
    int beg = __builtin_amdgcn_readfirstlane(rp[node]);
    int end = __builtin_amdgcn_readfirstlane(rp[node + 1]);
    float ax = 0.f, ay = 0.f;
    for (int c0 = beg; c0 < end; c0 += 64) {
        int cnt = end - c0;
        if (cnt > 64) cnt = 64;
        int li = lane < cnt ? lane : 0;
        int2 r = rec[c0 + li];
        for (int jb = 0; jb < cnt; jb += 16) {
            int ssrc[16];
            float sw[16];
#pragma unroll
            for (int k = 0; k < 16; ++k) {
                int jj = jb + k;
                int jc = jj < cnt ? jj : 0;
                ssrc[k] = __builtin_amdgcn_readlane(r.x, jc);
                float wv = __uint_as_float((unsigned int)__builtin_amdgcn_readlane(r.y, jc));
                sw[k] = (jj < cnt) ? wv : 0.f;
            }
            unsigned int g[16];
#pragma unroll
            for (int k = 0; k < 16; ++k) g[k] = hin[(size_t)ssrc[k] * 64 + lane];
#pragma unroll
            for (int k = 0; k < 16; ++k) {
                ax = fmaf(sw[k], __uint_as_float(g[k] << 16), ax);
                ay = fmaf(sw[k], __uint_as_float(g[k] & 0xffff0000u), ay);
            }
        }
    }
    if (OUTBF) {
        ((unsigned int*)hout)[(size_t)node * 64 + lane] = packbf2(ax, ay);
    } else {
        float2 o;
        o.x = ax;
        o.y = ay;
        ((float2*)hout)[(size_t)node * 64 + lane] = o;
    }
}

// ---------------- launch ----------------

extern "C" void kernel_launch(void* const* d_in, const int* in_sizes, int n_in,
                              void* d_out, int out_size, void* d_ws, size_t ws_size,
                              hipStream_t stream) {
    const float* x = (const float*)d_in[0];
    const float* W = (const float*)d_in[1];
    const float* b = (const float*)d_in[2];
    const int* esrc = (const int*)d_in[3];
    const int* edst = (const int*)d_in[4];
    const float* ew = (const float*)d_in[5];
    int N = in_sizes[0] / IN_DIM;
    int E = in_sizes[3];
    int NB = (N + BKT_NODES - 1) >> BKT_SHIFT;  // 196

    char* p = (char*)d_ws;
    auto alloc = [&](size_t bytes) -> void* {
        void* r = (void*)p;
        p += (bytes + 255) & ~(size_t)255;
        return r;
    };
    unsigned short* hbf = (unsigned short*)alloc((size_t)N * EMB * 2);
    unsigned short* h1bf = (unsigned short*)alloc((size_t)N * EMB * 2);
    unsigned short* wtg = (unsigned short*)alloc((size_t)IN_DIM * EMB * 2);
    unsigned short* xbf = (unsigned short*)alloc((size_t)N * IN_DIM * 2);
    int* ghist = (int*)alloc(256 * 4);
    int* gcursor = (int*)alloc(256 * 4);
    int* bucket_off = (int*)alloc((size_t)(NB + 1) * 4);
    int* row_ptr = (int*)alloc((size_t)(N + 1) * 4);
    int2* binned = (int2*)alloc((size_t)E * 8);
    int2* sorted = (int2*)alloc((size_t)E * 8);

    hipMemsetAsync(ghist, 0, 256 * 4, stream);
    prep<<<2048, 256, 0, stream>>>(W, wtg, x, xbf, N * IN_DIM / 8, edst, ghist, E);
    bucket_scan<<<1, 256, 0, stream>>>(ghist, bucket_off, gcursor, row_ptr, NB, N, E);
    bin_scatter<<<(E + BINE - 1) / BINE, 512, 0, stream>>>(esrc, edst, ew, gcursor, binned, E);
    bucket_sort<<<NB, 1024, 0, stream>>>(binned, bucket_off, sorted, row_ptr, N);

    gemm_mfma<<<(N + 127) / 128, 256, 0, stream>>>(xbf, wtg, b, hbf, N);
    prop_g<1><<<(N + 3) / 4, 256, 0, stream>>>((const unsigned int*)hbf, h1bf, row_ptr, sorted, N);
    prop_g<0><<<(N + 3) / 4, 256, 0, stream>>>((const unsigned int*)h1bf, d_out, row_ptr, sorted, N);
}

// Round 17
// 219.674 us; speedup vs baseline: 1.2078x; 1.0486x over previous
//
#include <hip/hip_runtime.h>

#define IN_DIM 256
#define EMB 128
// bucket = dst >> 9 (512 nodes per bucket). Requires N <= 131072 (src packed in 17 bits).
#define BKT_SHIFT 9
#define BKT_NODES 512
#define BINE 4096       // edges per bin_scatter block
#define SCAP 12288      // bucket_sort LDS staging capacity (mean ~8163, huge margin)

typedef __attribute__((ext_vector_type(8))) short short8;
typedef __attribute__((ext_vector_type(4))) float f32x4;

__device__ __forceinline__ unsigned short bf16rtne(float f) {
    unsigned int u = __float_as_uint(f);
    return (unsigned short)((u + 0x7fffu + ((u >> 16) & 1u)) >> 16);
}

__device__ __forceinline__ unsigned int packbf2(float lo, float hi) {
    return ((unsigned int)bf16rtne(hi) << 16) | (unsigned int)bf16rtne(lo);
}

// packed f32x8 -> bf16x8 via native cvt_pk (RNE)
__device__ __forceinline__ short8 pack8(float4 f0, float4 f1) {
    union { uint4 u; short8 s; } U;
    asm("v_cvt_pk_bf16_f32 %0, %1, %2" : "=v"(U.u.x) : "v"(f0.x), "v"(f0.y));
    asm("v_cvt_pk_bf16_f32 %0, %1, %2" : "=v"(U.u.y) : "v"(f0.z), "v"(f0.w));
    asm("v_cvt_pk_bf16_f32 %0, %1, %2" : "=v"(U.u.z) : "v"(f1.x), "v"(f1.y));
    asm("v_cvt_pk_bf16_f32 %0, %1, %2" : "=v"(U.u.w) : "v"(f1.z), "v"(f1.w));
    return U.s;
}

// ---------------- prep: wt_cast + bucket_hist (x cast folded into gemm) ----------------

__global__ __launch_bounds__(256) void prep(const float* __restrict__ W,
                                            unsigned short* __restrict__ wtg,
                                            const int* __restrict__ dst,
                                            int* __restrict__ ghist, int E) {
    int t = threadIdx.x;
    int gsz = gridDim.x * 256;
    int gid = blockIdx.x * 256 + t;
    // W^T cast (tiny)
    for (int i = gid; i < IN_DIM * EMB; i += gsz) {
        int c = i & 127;
        int k = i >> 7;
        wtg[c * 256 + k] = bf16rtne(W[(size_t)k * 128 + c]);
    }
    // bucket histogram: int4 vectorized dst reads
    __shared__ int h[256];
    h[t] = 0;
    __syncthreads();
    int nE4 = E >> 2;
    for (int i = gid; i < nE4; i += gsz) {
        int4 d = ((const int4*)dst)[i];
        atomicAdd(&h[d.x >> BKT_SHIFT], 1);
        atomicAdd(&h[d.y >> BKT_SHIFT], 1);
        atomicAdd(&h[d.z >> BKT_SHIFT], 1);
        atomicAdd(&h[d.w >> BKT_SHIFT], 1);
    }
    for (int i = (nE4 << 2) + gid; i < E; i += gsz) atomicAdd(&h[dst[i] >> BKT_SHIFT], 1);
    __syncthreads();
    if (h[t]) atomicAdd(&ghist[t], h[t]);
}

// single block: exclusive scan of bucket counts -> bucket_off, gcursor
__global__ __launch_bounds__(256) void bucket_scan(const int* __restrict__ ghist,
                                                   int* __restrict__ bucket_off,
                                                   int* __restrict__ gcursor,
                                                   int* __restrict__ row_ptr,
                                                   int NB, int N, int E) {
    __shared__ int s[256];
    int t = threadIdx.x;
    int v = (t < NB) ? ghist[t] : 0;
    s[t] = v;
    __syncthreads();
    for (int off = 1; off < 256; off <<= 1) {
        int u = (t >= off) ? s[t - off] : 0;
        __syncthreads();
        s[t] += u;
        __syncthreads();
    }
    int excl = s[t] - v;
    if (t < NB) {
        bucket_off[t] = excl;
        gcursor[t] = excl;
    }
    if (t == 0) {
        bucket_off[NB] = E;
        row_ptr[N] = E;
    }
}

// ---------------- CSR build: bin edges by bucket, LDS-staged, streaming out ----------------

__global__ __launch_bounds__(512) void bin_scatter(const int* __restrict__ src,
                                                   const int* __restrict__ dst,
                                                   const float* __restrict__ w,
                                                   int* __restrict__ gcursor,
                                                   int2* __restrict__ binned, int E) {
    __shared__ int h[256];
    __shared__ int lbase[256];
    __shared__ int gbase[256];
    __shared__ int lcur[256];
    __shared__ int2 stage[BINE];         // 32 KB
    __shared__ unsigned char sb[BINE];   // slot -> bucket, 4 KB
    int t = threadIdx.x;
    int e0 = blockIdx.x * BINE;
    int e1 = min(E, e0 + BINE);
    int n = e1 - e0;

    int ed[8], es[8];
    float ewv[8];
#pragma unroll
    for (int j = 0; j < 8; ++j) {
        int i = e0 + t + j * 512;
        if (i < e1) {
            ed[j] = dst[i];
            es[j] = src[i];
            ewv[j] = w[i];
        } else
            ed[j] = -1;
    }
    if (t < 256) h[t] = 0;
    __syncthreads();
#pragma unroll
    for (int j = 0; j < 8; ++j)
        if (ed[j] >= 0) atomicAdd(&h[ed[j] >> BKT_SHIFT], 1);
    __syncthreads();
    int v = 0;
    if (t < 256) {
        v = h[t];
        lbase[t] = v;
    }
    __syncthreads();
    for (int off = 1; off < 256; off <<= 1) {
        int u = 0;
        if (t < 256 && t >= off) u = lbase[t - off];
        __syncthreads();
        if (t < 256) lbase[t] += u;
        __syncthreads();
    }
    if (t < 256) {
        lbase[t] -= v;  // exclusive
        lcur[t] = lbase[t];
        gbase[t] = v ? atomicAdd(&gcursor[t], v) : 0;
    }
    __syncthreads();
#pragma unroll
    for (int j = 0; j < 8; ++j) {
        if (ed[j] >= 0) {
            int b = ed[j] >> BKT_SHIFT;
            int p = atomicAdd(&lcur[b], 1);
            int2 r;
            r.x = es[j] | ((ed[j] & (BKT_NODES - 1)) << 17);
            r.y = __float_as_int(ewv[j]);
            stage[p] = r;
            sb[p] = (unsigned char)b;
        }
    }
    __syncthreads();
    for (int i = t; i < n; i += 512) {
        int b = sb[i];
        binned[gbase[b] + (i - lbase[b])] = stage[i];
    }
}

// ---------------- CSR build: per-bucket counting sort, LDS-staged, streaming out ----------------

__global__ __launch_bounds__(1024) void bucket_sort(const int2* __restrict__ binned,
                                                    const int* __restrict__ bucket_off,
                                                    int2* __restrict__ sorted,
                                                    int* __restrict__ row_ptr, int N) {
    __shared__ int cnt[BKT_NODES];
    __shared__ int cur[BKT_NODES];
    __shared__ int scn[BKT_NODES];
    __shared__ int2 stage[SCAP];  // 96 KB
    int t = threadIdx.x;
    int b = blockIdx.x;
    int node0 = b << BKT_SHIFT;
    int nn = min(BKT_NODES, N - node0);
    int beg = bucket_off[b];
    int endb = bucket_off[b + 1];
    int n = endb - beg;
    if (t < BKT_NODES) cnt[t] = 0;
    __syncthreads();
    for (int i = beg + t; i < endb; i += 1024) {
        int ld = ((unsigned int)binned[i].x) >> 17;
        atomicAdd(&cnt[ld], 1);
    }
    __syncthreads();
    int v = 0;
    if (t < BKT_NODES) {
        v = cnt[t];
        scn[t] = v;
    }
    __syncthreads();
    for (int off = 1; off < BKT_NODES; off <<= 1) {
        int u = 0;
        if (t < BKT_NODES && t >= off) u = scn[t - off];
        __syncthreads();
        if (t < BKT_NODES) scn[t] += u;
        __syncthreads();
    }
    if (t < BKT_NODES) {
        int excl = scn[t] - v;
        cur[t] = excl;
        if (t < nn) row_ptr[node0 + t] = beg + excl;
    }
    __syncthreads();
    if (n <= SCAP) {
        for (int i = beg + t; i < endb; i += 1024) {
            int2 r = binned[i];
            int ld = ((unsigned int)r.x) >> 17;
            int p = atomicAdd(&cur[ld], 1);
            r.x &= 0x1FFFF;
            stage[p] = r;
        }
        __syncthreads();
        for (int i = t; i < n; i += 1024) sorted[beg + i] = stage[i];  // sequential
    } else {
        for (int i = beg + t; i < endb; i += 1024) {
            int2 r = binned[i];
            int ld = ((unsigned int)r.x) >> 17;
            int p = atomicAdd(&cur[ld], 1);
            r.x &= 0x1FFFF;
            sorted[beg + p] = r;
        }
    }
}

// ---------------- MFMA GEMM: h = relu(x@W + b), x f32 read directly ----------------
// m97 pattern, 128x128 tile, BK=64, 4 waves. A staged as f32 (32 KB) via
// global_load_lds with PRE-SWIZZLED source (16B chunk c' = c ^ (r&7), c in
// [0,16)); f32->bf16 pack at frag-read (2x ds_read_b128 + 4 cvt_pk per frag).
// B (bf16) path unchanged. 48 KB LDS -> 3 blocks/CU.

__global__ __launch_bounds__(256) void gemm_mfma(const float* __restrict__ x,
                                                 const unsigned short* __restrict__ wtg,
                                                 const float* __restrict__ bias,
                                                 unsigned short* __restrict__ hbf, int N) {
    __shared__ float Asf[128][64];          // 32 KB
    __shared__ unsigned short Bs[128][64];  // 16 KB
    int tid = threadIdx.x;
    int wv = tid >> 6;
    int lane = tid & 63;
    int lr = lane & 15;
    int lg = lane >> 4;
    int wr = wv * 32;
    int row0 = blockIdx.x * 128;

    f32x4 acc[2][8];
#pragma unroll
    for (int m = 0; m < 2; ++m)
#pragma unroll
        for (int n = 0; n < 8; ++n) acc[m][n] = (f32x4){0.f, 0.f, 0.f, 0.f};

    for (int kb = 0; kb < IN_DIM; kb += 64) {
        // stage A (f32): 2048 chunks of 16B, 8 per thread, linear LDS dest,
        // pre-swizzled global source
#pragma unroll
        for (int i = 0; i < 8; ++i) {
            int p = 256 * i + wv * 64 + lane;
            int r = p >> 4;
            int c = p & 15;
            int gr = row0 + r;
            if (gr >= N) gr = N - 1;
            const float* ga = x + (size_t)gr * IN_DIM + kb + ((c ^ (r & 7)) << 2);
            __builtin_amdgcn_global_load_lds(
                (const __attribute__((address_space(1))) void*)ga,
                (__attribute__((address_space(3))) void*)((char*)&Asf[0][0] + (size_t)(256 * i + wv * 64) * 16),
                16, 0, 0);
        }
        // stage B (bf16): 1024 chunks, 4 per thread (unchanged geometry)
#pragma unroll
        for (int i = 0; i < 4; ++i) {
            int p = 256 * i + wv * 64 + lane;
            int r = p >> 3;
            int c = p & 7;
            const unsigned short* gb = wtg + (size_t)r * IN_DIM + kb + ((c ^ (r & 7)) * 8);
            __builtin_amdgcn_global_load_lds(
                (const __attribute__((address_space(1))) void*)gb,
                (__attribute__((address_space(3))) void*)((char*)&Bs[0][0] + (size_t)(256 * i + wv * 64) * 16),
                16, 0, 0);
        }
        __syncthreads();

        // A frags: global chunk ch -> LDS slot ch ^ (r&7); pack f32x8 -> bf16x8
        short8 a[2][2];
#pragma unroll
        for (int m = 0; m < 2; ++m)
#pragma unroll
            for (int kk = 0; kk < 2; ++kk) {
                int r = wr + m * 16 + lr;
                int s = r & 7;
                int ch0 = kk * 8 + lg * 2;
                float4 f0 = *(const float4*)&Asf[r][(ch0 ^ s) << 2];
                float4 f1 = *(const float4*)&Asf[r][((ch0 + 1) ^ s) << 2];
                a[m][kk] = pack8(f0, f1);
            }
#pragma unroll
        for (int n = 0; n < 8; ++n) {
            int cc = n * 16 + lr;
            int sw = cc & 7;
            short8 b0 = *(const short8*)&Bs[cc][(((0 * 4 + lg) ^ sw) * 8)];
            short8 b1 = *(const short8*)&Bs[cc][(((1 * 4 + lg) ^ sw) * 8)];
            acc[0][n] = __builtin_amdgcn_mfma_f32_16x16x32_bf16(a[0][0], b0, acc[0][n], 0, 0, 0);
            acc[0][n] = __builtin_amdgcn_mfma_f32_16x16x32_bf16(a[0][1], b1, acc[0][n], 0, 0, 0);
            acc[1][n] = __builtin_amdgcn_mfma_f32_16x16x32_bf16(a[1][0], b0, acc[1][n], 0, 0, 0);
            acc[1][n] = __builtin_amdgcn_mfma_f32_16x16x32_bf16(a[1][1], b1, acc[1][n], 0, 0, 0);
        }
        __syncthreads();
    }

#pragma unroll
    for (int n = 0; n < 8; ++n) {
        int c = n * 16 + lr;
        float bv = bias[c];
#pragma unroll
        for (int m = 0; m < 2; ++m) {
#pragma unroll
            for (int j = 0; j < 4; ++j) {
                int r = row0 + wr + m * 16 + lg * 4 + j;
                if (r < N) {
                    float v = fmaxf(acc[m][n][j] + bv, 0.f);
                    hbf[(size_t)r * EMB + c] = bf16rtne(v);
                }
            }
        }
    }
}

// ---------------- propagation: wave per node, readlane broadcasts, 16-deep gathers ----

template <int OUTBF>
__global__ __launch_bounds__(256) void prop_g(const unsigned int* __restrict__ hin,
                                              void* __restrict__ hout,
                                              const int* __restrict__ rp,
                                              const int2* __restrict__ rec, int N) {
    int wvid = threadIdx.x >> 6;
    int lane = threadIdx.x & 63;
    int node = blockIdx.x * 4 + wvid;
    if (node >= N) return;
    int beg = __builtin_amdgcn_readfirstlane(rp[node]);
    int end = __builtin_amdgcn_readfirstlane(rp[node + 1]);
    float ax = 0.f, ay = 0.f;
    for (int c0 = beg; c0 < end; c0 += 64) {
        int cnt = end - c0;
        if (cnt > 64) cnt = 64;
        int li = lane < cnt ? lane : 0;
        int2 r = rec[c0 + li];
        for (int jb = 0; jb < cnt; jb += 16) {
            int ssrc[16];
            float sw[16];
#pragma unroll
            for (int k = 0; k < 16; ++k) {
                int jj = jb + k;
                int jc = jj < cnt ? jj : 0;
                ssrc[k] = __builtin_amdgcn_readlane(r.x, jc);
                float wv = __uint_as_float((unsigned int)__builtin_amdgcn_readlane(r.y, jc));
                sw[k] = (jj < cnt) ? wv : 0.f;
            }
            unsigned int g[16];
#pragma unroll
            for (int k = 0; k < 16; ++k) g[k] = hin[(size_t)ssrc[k] * 64 + lane];
#pragma unroll
            for (int k = 0; k < 16; ++k) {
                ax = fmaf(sw[k], __uint_as_float(g[k] << 16), ax);
                ay = fmaf(sw[k], __uint_as_float(g[k] & 0xffff0000u), ay);
            }
        }
    }
    if (OUTBF) {
        ((unsigned int*)hout)[(size_t)node * 64 + lane] = packbf2(ax, ay);
    } else {
        float2 o;
        o.x = ax;
        o.y = ay;
        ((float2*)hout)[(size_t)node * 64 + lane] = o;
    }
}

// ---------------- launch ----------------

extern "C" void kernel_launch(void* const* d_in, const int* in_sizes, int n_in,
                              void* d_out, int out_size, void* d_ws, size_t ws_size,
                              hipStream_t stream) {
    const float* x = (const float*)d_in[0];
    const float* W = (const float*)d_in[1];
    const float* b = (const float*)d_in[2];
    const int* esrc = (const int*)d_in[3];
    const int* edst = (const int*)d_in[4];
    const float* ew = (const float*)d_in[5];
    int N = in_sizes[0] / IN_DIM;
    int E = in_sizes[3];
    int NB = (N + BKT_NODES - 1) >> BKT_SHIFT;  // 196

    char* p = (char*)d_ws;
    auto alloc = [&](size_t bytes) -> void* {
        void* r = (void*)p;
        p += (bytes + 255) & ~(size_t)255;
        return r;
    };
    unsigned short* hbf = (unsigned short*)alloc((size_t)N * EMB * 2);
    unsigned short* h1bf = (unsigned short*)alloc((size_t)N * EMB * 2);
    unsigned short* wtg = (unsigned short*)alloc((size_t)IN_DIM * EMB * 2);
    int* ghist = (int*)alloc(256 * 4);
    int* gcursor = (int*)alloc(256 * 4);
    int* bucket_off = (int*)alloc((size_t)(NB + 1) * 4);
    int* row_ptr = (int*)alloc((size_t)(N + 1) * 4);
    int2* binned = (int2*)alloc((size_t)E * 8);
    int2* sorted = (int2*)alloc((size_t)E * 8);

    hipMemsetAsync(ghist, 0, 256 * 4, stream);
    prep<<<1024, 256, 0, stream>>>(W, wtg, edst, ghist, E);
    bucket_scan<<<1, 256, 0, stream>>>(ghist, bucket_off, gcursor, row_ptr, NB, N, E);
    bin_scatter<<<(E + BINE - 1) / BINE, 512, 0, stream>>>(esrc, edst, ew, gcursor, binned, E);
    bucket_sort<<<NB, 1024, 0, stream>>>(binned, bucket_off, sorted, row_ptr, N);

    gemm_mfma<<<(N + 127) / 128, 256, 0, stream>>>(x, wtg, b, hbf, N);
    prop_g<1><<<(N + 3) / 4, 256, 0, stream>>>((const unsigned int*)hbf, h1bf, row_ptr, sorted, N);
    prop_g<0><<<(N + 3) / 4, 256, 0, stream>>>((const unsigned int*)h1bf, d_out, row_ptr, sorted, N);
}